// Round 10
// baseline (5996.519 us; speedup 1.0000x reference)
//
#include <hip/hip_runtime.h>
#include <cstdint>
#include <cstddef>

#define T_STEPS 256
#define B_DIM   64
#define D_DIM   768
#define R_DIM   2048
#define NBLK    256
#define NTHR    512

// LDS layout (dynamic): Whi frag [64 chunks][64 lanes][8 bf16] = 64 KB
//                       Wlo frag same                          = 64 KB
//                       partial  [8 waves][64 lanes][4 f32]    =  8 KB
#define S_WHI_OFF  0
#define S_WLO_OFF  65536
#define S_PART_OFF 131072
#define S_TOTAL    139264

using short8 = __attribute__((ext_vector_type(8))) short;
using f32x4  = __attribute__((ext_vector_type(4))) float;

__device__ __forceinline__ uint16_t f2bf(float f) {
  uint32_t u = __builtin_bit_cast(uint32_t, f);
  u += 0x7fffu + ((u >> 16) & 1u);   // round-to-nearest-even
  return (uint16_t)(u >> 16);
}
__device__ __forceinline__ float bf2f(uint16_t h) {
  uint32_t u = ((uint32_t)h) << 16;
  return __builtin_bit_cast(float, u);
}

// agent-scope write-through accesses (coherent at L3)
__device__ __forceinline__ void st32_agent(uint32_t* p, uint32_t v) {
  __hip_atomic_store(p, v, __ATOMIC_RELAXED, __HIP_MEMORY_SCOPE_AGENT);
}
__device__ __forceinline__ void st16_agent(uint16_t* p, uint16_t v) {
  __hip_atomic_store(p, v, __ATOMIC_RELAXED, __HIP_MEMORY_SCOPE_AGENT);
}
__device__ __forceinline__ uint32_t ld32_agent(const uint32_t* p) {
  return __hip_atomic_load(p, __ATOMIC_RELAXED, __HIP_MEMORY_SCOPE_AGENT);
}

// ---- prep kernels ----
__global__ void k_split_w(const float* __restrict__ w, uint16_t* __restrict__ hi,
                          uint16_t* __restrict__ lo, int n) {
  for (int i = blockIdx.x * blockDim.x + threadIdx.x; i < n;
       i += gridDim.x * blockDim.x) {
    float f = w[i];
    uint16_t h = f2bf(f);
    hi[i] = h;
    lo[i] = f2bf(f - bf2f(h));
  }
}

__global__ void k_tobf(const float* __restrict__ src, uint16_t* __restrict__ dst,
                       int n) {
  for (int i = blockIdx.x * blockDim.x + threadIdx.x; i < n;
       i += gridDim.x * blockDim.x)
    dst[i] = f2bf(src[i]);
}

__global__ void k_init_x(const float* __restrict__ init,
                         uint16_t* __restrict__ hi, uint16_t* __restrict__ lo,
                         uint32_t* __restrict__ flags) {
  int i = blockIdx.x * blockDim.x + threadIdx.x;
  if (i < NBLK * 16) flags[i] = 0u;          // 64B-spaced barrier flags
  if (i < B_DIM * R_DIM) {
    float f = init[i & (R_DIM - 1)];
    uint16_t h = f2bf(f);
    hi[i] = h;
    lo[i] = f2bf(f - bf2f(h));
  }
}

// ---- persistent ESN kernel, dataflow-synchronized ----
// 256 blocks: bid>>7 = batch half (32 rows), bid&127 = n-tile (16 cols).
// 8 waves: w>>2 = m-subtile (16 rows), w&3 = K-split group kg (512 k each).
// NO global barrier. Wave kg consumes x cols [kg*512, kg*512+512) of its half,
// produced by exactly 32 blocks (n-tiles kg*32..kg*32+31). Each wave polls
// only those 32 flags, then does its OWN acquire fence (L1/L2 inv), then
// plain cached loads. Block flag = "my x_{t+1} contributions visible at L3"
// (all 8 waves' write-through stores acked, enforced by __syncthreads drain).
// WAR on the 2-deep x ping-pong is protected by the block's own wave-union
// dependency: a block can't overwrite buf[t&1] at step t+2 until the whole
// half has flagged >= t+2, i.e. all t+1 readers are done.
__global__ __launch_bounds__(NTHR, 2)
void k_persist(const uint16_t* __restrict__ Whi, const uint16_t* __restrict__ Wlo,
               const uint16_t* __restrict__ Iwb, const uint16_t* __restrict__ ubf,
               const float* __restrict__ init,
               uint16_t* __restrict__ xh, uint16_t* __restrict__ xl,
               const float* __restrict__ bias, const int* __restrict__ lengths,
               float* __restrict__ out, uint32_t* __restrict__ flags)
{
  extern __shared__ char smem[];
  uint16_t* s_whi  = (uint16_t*)(smem + S_WHI_OFF);
  uint16_t* s_wlo  = (uint16_t*)(smem + S_WLO_OFF);
  float*    s_part = (float*)(smem + S_PART_OFF);

  const int bid  = blockIdx.x;
  const int h    = bid >> 7;           // batch half
  const int n0   = (bid & 127) * 16;   // output column base
  const int tid  = threadIdx.x;
  const int w    = tid >> 6;
  const int lane = tid & 63;
  const int kg   = w & 3;              // K-split group
  const int mt   = h * 32 + (w >> 2) * 16;  // batch-row tile base
  const int fr   = lane & 15;
  const int koffe = (lane >> 4) << 3;  // 0,8,16,24 element offset

  // preload W slice (16 cols x 2048 k, hi+lo) into LDS, fragment layout
  for (int s = tid; s < 4096; s += NTHR) {
    int ch = s >> 6, l = s & 63;
    size_t g = (size_t)(n0 + (l & 15)) * R_DIM + (size_t)ch * 32 + ((l >> 4) << 3);
    *(short8*)(s_whi + (size_t)s * 8) = *(const short8*)(Whi + g);
    *(short8*)(s_wlo + (size_t)s * 8) = *(const short8*)(Wlo + g);
  }

  // Iw fragments: step-invariant -> registers, loaded ONCE
  short8 biv[6];
  {
    const uint16_t* iw_row = Iwb + (size_t)(n0 + fr) * D_DIM + kg * 192 + koffe;
#pragma unroll
    for (int i = 0; i < 6; ++i) biv[i] = *(const short8*)(iw_row + i * 32);
  }
  __syncthreads();

  // this wave's producer flag pointer (32 producers, lanes 0..31; dup for 32..63)
  const uint32_t* my_flag = flags + (size_t)(h * 128 + kg * 32 + (lane & 31)) * 16;

  // epilogue mapping: 512 threads x 1 element (row r, col c of the 32x16 tile)
  const int r_ep = tid >> 4;           // 0..31
  const int c_ep = tid & 15;           // 0..15
  const int b_ep = h * 32 + r_ep;
  const float bias_ep = bias[n0 + c_ep];
  float xo = init[n0 + c_ep];          // running state in registers
  const int len_ep = lengths[b_ep];
  const int mw_ep = (r_ep >> 4) << 2;                      // wave group base
  const int l_ep  = ((((r_ep & 15) >> 2)) << 4) | c_ep;    // lane within wave
  const int j_ep  = r_ep & 3;

  // prefetch u fragments for step 0
  short8 au[6];
  {
    const uint16_t* u_row = ubf + ((size_t)0 * B_DIM + mt + fr) * D_DIM + kg * 192 + koffe;
#pragma unroll
    for (int i = 0; i < 6; ++i) au[i] = *(const short8*)(u_row + i * 32);
  }

  for (int t = 0; t < T_STEPS; ++t) {
    const int cur = t & 1, nxt = cur ^ 1;

    // ---- per-wave producer wait + per-wave acquire fence ----
    if (t > 0) {
      const uint32_t tgt = (uint32_t)t;  // producers have completed step t-1
      for (;;) {
        bool ok = (ld32_agent(my_flag) >= tgt);
        if (__all(ok)) break;
        __builtin_amdgcn_s_sleep(1);
      }
      // invalidate this CU's L1 + the XCD L2 so our x loads refetch from L3.
      // Safe per-wave: L2 fills of x lines only happen via post-wait reads.
      __builtin_amdgcn_fence(__ATOMIC_ACQUIRE, "agent");
    }

    const uint16_t* xh_row = xh + (size_t)cur * B_DIM * R_DIM + (size_t)(mt + fr) * R_DIM + koffe;
    const uint16_t* xl_row = xl + (size_t)cur * B_DIM * R_DIM + (size_t)(mt + fr) * R_DIM + koffe;

    // ---- issue x loads; input projection (reg-only) fills the latency ----
    short8 ahv[16], alv[16];
#pragma unroll 16
    for (int i = 0; i < 16; ++i) {
      const int ch = kg * 16 + i;
      ahv[i] = *(const short8*)(xh_row + ch * 32);
      alv[i] = *(const short8*)(xl_row + ch * 32);
    }
    f32x4 acc = {0.f, 0.f, 0.f, 0.f};
#pragma unroll
    for (int i = 0; i < 6; ++i)
      acc = __builtin_amdgcn_mfma_f32_16x16x32_bf16(au[i], biv[i], acc, 0, 0, 0);

    // ---- recurrent MFMA phase (split bf16, K-split) ----
#pragma unroll 16
    for (int i = 0; i < 16; ++i) {
      const int ch = kg * 16 + i;
      short8 bh = *(const short8*)(s_whi + (size_t)(ch * 64 + lane) * 8);
      short8 bl = *(const short8*)(s_wlo + (size_t)(ch * 64 + lane) * 8);
      acc = __builtin_amdgcn_mfma_f32_16x16x32_bf16(ahv[i], bh, acc, 0, 0, 0);
      acc = __builtin_amdgcn_mfma_f32_16x16x32_bf16(ahv[i], bl, acc, 0, 0, 0);
      acc = __builtin_amdgcn_mfma_f32_16x16x32_bf16(alv[i], bh, acc, 0, 0, 0);
    }

    // ---- K-split reduce through LDS ----
    *(f32x4*)(s_part + ((size_t)w * 64 + lane) * 4) = acc;
    __syncthreads();

    // ---- epilogue: 1 element/thread; write-through x stores ----
    {
      float pre = bias_ep;
#pragma unroll
      for (int g2 = 0; g2 < 4; ++g2)
        pre += s_part[(mw_ep + g2) * 256 + l_ep * 4 + j_ep];
      float xn = 0.5f * xo + 0.5f * tanhf(pre);
      if (t >= len_ep) xn = 0.0f;
      xo = xn;
      out[((size_t)b_ep * T_STEPS + t) * R_DIM + n0 + c_ep] = xn;  // plain store
      uint16_t* xhn = xh + (size_t)nxt * B_DIM * R_DIM;
      uint16_t* xln = xl + (size_t)nxt * B_DIM * R_DIM;
      const uint16_t hh = f2bf(xn);
      st16_agent(xhn + (size_t)b_ep * R_DIM + n0 + c_ep, hh);
      st16_agent(xln + (size_t)b_ep * R_DIM + n0 + c_ep, f2bf(xn - bf2f(hh)));
    }

    if (t == T_STEPS - 1) break;

    // ---- block arrival: all waves' stores acked at L3, then publish flag ----
    asm volatile("s_waitcnt vmcnt(0)" ::: "memory");
    __syncthreads();                   // all 8 waves drained
    if (tid == 0) st32_agent(flags + (size_t)bid * 16, (uint32_t)(t + 1));

    // prefetch next step's u (hides under the next poll)
    {
      const uint16_t* u_row = ubf + ((size_t)(t + 1) * B_DIM + mt + fr) * D_DIM + kg * 192 + koffe;
#pragma unroll
      for (int i = 0; i < 6; ++i) au[i] = *(const short8*)(u_row + i * 32);
    }
  }
}

extern "C" void kernel_launch(void* const* d_in, const int* in_sizes, int n_in,
                              void* d_out, int out_size, void* d_ws, size_t ws_size,
                              hipStream_t stream) {
  const float* embedded    = (const float*)d_in[0];
  const int*   lengths     = (const int*)d_in[1];
  const float* input_w     = (const float*)d_in[2];
  const float* reservoir_w = (const float*)d_in[3];
  const float* bias        = (const float*)d_in[4];
  const float* init        = (const float*)d_in[5];
  float* out = (float*)d_out;

  // workspace carve (~45 MB)
  char* p = (char*)d_ws;
  uint16_t* Whi = (uint16_t*)p; p += (size_t)R_DIM * R_DIM * 2;
  uint16_t* Wlo = (uint16_t*)p; p += (size_t)R_DIM * R_DIM * 2;
  uint16_t* Iwb = (uint16_t*)p; p += (size_t)R_DIM * D_DIM * 2;
  uint16_t* ubf = (uint16_t*)p; p += (size_t)T_STEPS * B_DIM * D_DIM * 2;
  uint16_t* xh  = (uint16_t*)p; p += (size_t)2 * B_DIM * R_DIM * 2;
  uint16_t* xl  = (uint16_t*)p; p += (size_t)2 * B_DIM * R_DIM * 2;
  uint32_t* flags = (uint32_t*)p; p += (size_t)NBLK * 16 * 4;

  k_split_w<<<1024, 256, 0, stream>>>(reservoir_w, Whi, Wlo, R_DIM * R_DIM);
  k_tobf<<<512, 256, 0, stream>>>(input_w, Iwb, R_DIM * D_DIM);
  k_tobf<<<2048, 256, 0, stream>>>(embedded, ubf, T_STEPS * B_DIM * D_DIM);
  k_init_x<<<(B_DIM * R_DIM) / 256, 256, 0, stream>>>(init, xh, xl, flags);

  (void)hipFuncSetAttribute((const void*)k_persist,
                            hipFuncAttributeMaxDynamicSharedMemorySize, S_TOTAL);

  void* args[] = {(void*)&Whi, (void*)&Wlo, (void*)&Iwb, (void*)&ubf,
                  (void*)&init, (void*)&xh, (void*)&xl, (void*)&bias,
                  (void*)&lengths, (void*)&out, (void*)&flags};
  (void)hipLaunchCooperativeKernel((const void*)k_persist, dim3(NBLK), dim3(NTHR),
                                   args, S_TOTAL, stream);
}

// Round 12
// 1959.304 us; speedup vs baseline: 3.0605x; 3.0605x over previous
//
#include <hip/hip_runtime.h>
#include <cstdint>
#include <cstddef>

#define T_STEPS 256
#define B_DIM   64
#define D_DIM   768
#define R_DIM   2048
#define NBLK    256
#define NTHR    512

// LDS layout (dynamic): Whi frag [64 chunks][64 lanes][8 bf16] = 64 KB
//                       Wlo frag same                          = 64 KB
//                       partial  [8 waves][64 lanes][4 f32]    =  8 KB
#define S_WHI_OFF  0
#define S_WLO_OFF  65536
#define S_PART_OFF 131072
#define S_TOTAL    139264

using short8 = __attribute__((ext_vector_type(8))) short;
using f32x4  = __attribute__((ext_vector_type(4))) float;

__device__ __forceinline__ uint16_t f2bf(float f) {
  uint32_t u = __builtin_bit_cast(uint32_t, f);
  u += 0x7fffu + ((u >> 16) & 1u);   // round-to-nearest-even
  return (uint16_t)(u >> 16);
}
__device__ __forceinline__ float bf2f(uint16_t h) {
  uint32_t u = ((uint32_t)h) << 16;
  return __builtin_bit_cast(float, u);
}

// agent-scope write-through accesses (coherent at L3)
__device__ __forceinline__ void st32_agent(uint32_t* p, uint32_t v) {
  __hip_atomic_store(p, v, __ATOMIC_RELAXED, __HIP_MEMORY_SCOPE_AGENT);
}
__device__ __forceinline__ void st16_agent(uint16_t* p, uint16_t v) {
  __hip_atomic_store(p, v, __ATOMIC_RELAXED, __HIP_MEMORY_SCOPE_AGENT);
}
__device__ __forceinline__ uint32_t ld32_agent(const uint32_t* p) {
  return __hip_atomic_load(p, __ATOMIC_RELAXED, __HIP_MEMORY_SCOPE_AGENT);
}

// 16B L1/L2-bypassing load (system-coherent): served from L3, never stale.
// Issued WITHOUT a wait; caller must s_waitcnt vmcnt(0) + sched_barrier(0)
// before consuming (rule #18: compiler may hoist MFMAs past asm waits).
#define LDXB(dst, base, IMM)                                              \
  asm volatile("global_load_dwordx4 %0, %1, off offset:" IMM " sc0 sc1"   \
               : "=v"(dst) : "v"(base) : "memory")

// ---- prep kernels ----
__global__ void k_split_w(const float* __restrict__ w, uint16_t* __restrict__ hi,
                          uint16_t* __restrict__ lo, int n) {
  for (int i = blockIdx.x * blockDim.x + threadIdx.x; i < n;
       i += gridDim.x * blockDim.x) {
    float f = w[i];
    uint16_t h = f2bf(f);
    hi[i] = h;
    lo[i] = f2bf(f - bf2f(h));
  }
}

__global__ void k_tobf(const float* __restrict__ src, uint16_t* __restrict__ dst,
                       int n) {
  for (int i = blockIdx.x * blockDim.x + threadIdx.x; i < n;
       i += gridDim.x * blockDim.x)
    dst[i] = f2bf(src[i]);
}

__global__ void k_init_x(const float* __restrict__ init,
                         uint16_t* __restrict__ xb,
                         uint32_t* __restrict__ flags) {
  int i = blockIdx.x * blockDim.x + threadIdx.x;
  if (i < NBLK * 16) flags[i] = 0u;          // 64B-spaced barrier flags
  if (i < B_DIM * R_DIM) xb[i] = f2bf(init[i & (R_DIM - 1)]);
}

// ---- persistent ESN kernel (R7 structure, fence-free bypass x reads) ----
// 256 blocks: bid>>7 = batch half (32 rows), bid&127 = n-tile (16 cols).
// 8 waves: w>>2 = m-subtile (16 rows), w&3 = K-split group kg (512 k each).
// W hi+lo in LDS (fragment layout). Iw fragments in registers. x state is
// SINGLE bf16 (f32 running copy stays in epilogue registers for the leak
// term; only the MFMA operand is quantized). x writes = write-through sc1
// stores; x reads = sc0 sc1 bypass dwordx4 (L3-coherent) -> NO acquire fence
// anywhere, read-only data stays hot in L2. Half-grid flag barrier (R7).
__global__ __launch_bounds__(NTHR, 1)
void k_persist(const uint16_t* __restrict__ Whi, const uint16_t* __restrict__ Wlo,
               const uint16_t* __restrict__ Iwb, const uint16_t* __restrict__ ubf,
               const float* __restrict__ init, uint16_t* __restrict__ xb,
               const float* __restrict__ bias, const int* __restrict__ lengths,
               float* __restrict__ out, uint32_t* __restrict__ flags)
{
  extern __shared__ char smem[];
  uint16_t* s_whi  = (uint16_t*)(smem + S_WHI_OFF);
  uint16_t* s_wlo  = (uint16_t*)(smem + S_WLO_OFF);
  float*    s_part = (float*)(smem + S_PART_OFF);

  const int bid  = blockIdx.x;
  const int h    = bid >> 7;           // batch half
  const int n0   = (bid & 127) * 16;   // output column base
  const int tid  = threadIdx.x;
  const int w    = tid >> 6;
  const int lane = tid & 63;
  const int kg   = w & 3;              // K-split group
  const int mt   = h * 32 + (w >> 2) * 16;  // batch-row tile base
  const int fr   = lane & 15;
  const int koffe = (lane >> 4) << 3;  // 0,8,16,24 element offset

  // preload W slice (16 cols x 2048 k, hi+lo) into LDS, fragment layout
  for (int s = tid; s < 4096; s += NTHR) {
    int ch = s >> 6, l = s & 63;
    size_t g = (size_t)(n0 + (l & 15)) * R_DIM + (size_t)ch * 32 + ((l >> 4) << 3);
    *(short8*)(s_whi + (size_t)s * 8) = *(const short8*)(Whi + g);
    *(short8*)(s_wlo + (size_t)s * 8) = *(const short8*)(Wlo + g);
  }

  // Iw fragments: step-invariant -> registers, loaded ONCE
  short8 biv[6];
  {
    const uint16_t* iw_row = Iwb + (size_t)(n0 + fr) * D_DIM + kg * 192 + koffe;
#pragma unroll
    for (int i = 0; i < 6; ++i) biv[i] = *(const short8*)(iw_row + i * 32);
  }
  __syncthreads();

  // epilogue mapping: 512 threads x 1 element (row r, col c of the 32x16 tile)
  const int r_ep = tid >> 4;           // 0..31
  const int c_ep = tid & 15;           // 0..15
  const int b_ep = h * 32 + r_ep;
  const float bias_ep = bias[n0 + c_ep];
  float xo = init[n0 + c_ep];          // running state in f32 registers
  const int len_ep = lengths[b_ep];
  const int mw_ep = (r_ep >> 4) << 2;                      // wave group base
  const int l_ep  = ((((r_ep & 15) >> 2)) << 4) | c_ep;    // lane within wave
  const int j_ep  = r_ep & 3;

  // prefetch u fragments for step 0
  short8 au[6];
  {
    const uint16_t* u_row = ubf + ((size_t)0 * B_DIM + mt + fr) * D_DIM + kg * 192 + koffe;
#pragma unroll
    for (int i = 0; i < 6; ++i) au[i] = *(const short8*)(u_row + i * 32);
  }

  for (int t = 0; t < T_STEPS; ++t) {
    const int cur = t & 1, nxt = cur ^ 1;

    // ---- issue ALL 16 bypass x-loads (this wave's 512-col slice) ----
    const uint16_t* xrow = xb + (size_t)cur * B_DIM * R_DIM
                              + (size_t)(mt + fr) * R_DIM + kg * 512 + koffe;
    short8 ahv[16];
    LDXB(ahv[0],  xrow, "0");   LDXB(ahv[1],  xrow, "64");
    LDXB(ahv[2],  xrow, "128"); LDXB(ahv[3],  xrow, "192");
    LDXB(ahv[4],  xrow, "256"); LDXB(ahv[5],  xrow, "320");
    LDXB(ahv[6],  xrow, "384"); LDXB(ahv[7],  xrow, "448");
    LDXB(ahv[8],  xrow, "512"); LDXB(ahv[9],  xrow, "576");
    LDXB(ahv[10], xrow, "640"); LDXB(ahv[11], xrow, "704");
    LDXB(ahv[12], xrow, "768"); LDXB(ahv[13], xrow, "832");
    LDXB(ahv[14], xrow, "896"); LDXB(ahv[15], xrow, "960");

    // ---- input projection (register-only MFMAs fill the load latency) ----
    f32x4 acc = {0.f, 0.f, 0.f, 0.f};
#pragma unroll
    for (int i = 0; i < 6; ++i)
      acc = __builtin_amdgcn_mfma_f32_16x16x32_bf16(au[i], biv[i], acc, 0, 0, 0);

    // all bypass loads landed; fence the scheduler (rule #18)
    asm volatile("s_waitcnt vmcnt(0)" ::: "memory");
    __builtin_amdgcn_sched_barrier(0);

    // ---- recurrent MFMA phase (x_bf16 * (Whi + Wlo), K-split) ----
#pragma unroll 16
    for (int i = 0; i < 16; ++i) {
      const int ch = kg * 16 + i;
      short8 bh = *(const short8*)(s_whi + (size_t)(ch * 64 + lane) * 8);
      short8 bl = *(const short8*)(s_wlo + (size_t)(ch * 64 + lane) * 8);
      acc = __builtin_amdgcn_mfma_f32_16x16x32_bf16(ahv[i], bh, acc, 0, 0, 0);
      acc = __builtin_amdgcn_mfma_f32_16x16x32_bf16(ahv[i], bl, acc, 0, 0, 0);
    }

    // ---- K-split reduce through LDS ----
    *(f32x4*)(s_part + ((size_t)w * 64 + lane) * 4) = acc;
    __syncthreads();

    // ---- epilogue: 1 element/thread; f32 state in regs; bf16 wt store ----
    {
      float pre = bias_ep;
#pragma unroll
      for (int g2 = 0; g2 < 4; ++g2)
        pre += s_part[(mw_ep + g2) * 256 + l_ep * 4 + j_ep];
      float xn = 0.5f * xo + 0.5f * tanhf(pre);
      if (t >= len_ep) xn = 0.0f;
      xo = xn;
      out[((size_t)b_ep * T_STEPS + t) * R_DIM + n0 + c_ep] = xn;  // plain store
      st16_agent(xb + (size_t)nxt * B_DIM * R_DIM + (size_t)b_ep * R_DIM + n0 + c_ep,
                 f2bf(xn));
    }

    if (t == T_STEPS - 1) break;

    // ---- half-grid flag barrier (RMW-free, fence-free) ----
    asm volatile("s_waitcnt vmcnt(0)" ::: "memory");  // x stores acked at L3
    __syncthreads();                                  // whole block done
    // prefetch next step's u (read-only, L2-hot; hides under the poll)
    {
      const uint16_t* u_row = ubf + ((size_t)(t + 1) * B_DIM + mt + fr) * D_DIM + kg * 192 + koffe;
#pragma unroll
      for (int i = 0; i < 6; ++i) au[i] = *(const short8*)(u_row + i * 32);
    }
    if (w == 0) {
      st32_agent(flags + (size_t)bid * 16, (uint32_t)(t + 1));
      const uint32_t tgt = (uint32_t)(t + 1);
      const uint32_t* f0 = flags + (size_t)(h * 128 + 0 * 64 + lane) * 16;
      const uint32_t* f1 = flags + (size_t)(h * 128 + 1 * 64 + lane) * 16;
      for (;;) {
        bool ok = (ld32_agent(f0) >= tgt) & (ld32_agent(f1) >= tgt);
        if (__all(ok)) break;
        __builtin_amdgcn_s_sleep(1);
      }
    }
    __syncthreads();
  }
}

extern "C" void kernel_launch(void* const* d_in, const int* in_sizes, int n_in,
                              void* d_out, int out_size, void* d_ws, size_t ws_size,
                              hipStream_t stream) {
  const float* embedded    = (const float*)d_in[0];
  const int*   lengths     = (const int*)d_in[1];
  const float* input_w     = (const float*)d_in[2];
  const float* reservoir_w = (const float*)d_in[3];
  const float* bias        = (const float*)d_in[4];
  const float* init        = (const float*)d_in[5];
  float* out = (float*)d_out;

  // workspace carve (~44 MB)
  char* p = (char*)d_ws;
  uint16_t* Whi = (uint16_t*)p; p += (size_t)R_DIM * R_DIM * 2;
  uint16_t* Wlo = (uint16_t*)p; p += (size_t)R_DIM * R_DIM * 2;
  uint16_t* Iwb = (uint16_t*)p; p += (size_t)R_DIM * D_DIM * 2;
  uint16_t* ubf = (uint16_t*)p; p += (size_t)T_STEPS * B_DIM * D_DIM * 2;
  uint16_t* xb  = (uint16_t*)p; p += (size_t)2 * B_DIM * R_DIM * 2;
  uint32_t* flags = (uint32_t*)p; p += (size_t)NBLK * 16 * 4;

  k_split_w<<<1024, 256, 0, stream>>>(reservoir_w, Whi, Wlo, R_DIM * R_DIM);
  k_tobf<<<512, 256, 0, stream>>>(input_w, Iwb, R_DIM * D_DIM);
  k_tobf<<<2048, 256, 0, stream>>>(embedded, ubf, T_STEPS * B_DIM * D_DIM);
  k_init_x<<<(B_DIM * R_DIM) / 256, 256, 0, stream>>>(init, xb, flags);

  (void)hipFuncSetAttribute((const void*)k_persist,
                            hipFuncAttributeMaxDynamicSharedMemorySize, S_TOTAL);

  void* args[] = {(void*)&Whi, (void*)&Wlo, (void*)&Iwb, (void*)&ubf,
                  (void*)&init, (void*)&xb, (void*)&bias,
                  (void*)&lengths, (void*)&out, (void*)&flags};
  (void)hipLaunchCooperativeKernel((const void*)k_persist, dim3(NBLK), dim3(NTHR),
                                   args, S_TOTAL, stream);
}

// Round 13
// 1958.940 us; speedup vs baseline: 3.0611x; 1.0002x over previous
//
#include <hip/hip_runtime.h>
#include <cstdint>
#include <cstddef>

#define T_STEPS 256
#define B_DIM   64
#define D_DIM   768
#define R_DIM   2048
#define NBLK    256
#define NTHR    512

// LDS layout (dynamic): Whi frag [64 chunks][64 lanes][8 bf16] = 64 KB
//                       Wlo frag same                          = 64 KB
//                       partial  [8 waves][64 lanes][4 f32]    =  8 KB
#define S_WHI_OFF  0
#define S_WLO_OFF  65536
#define S_PART_OFF 131072
#define S_TOTAL    139264

using short8 = __attribute__((ext_vector_type(8))) short;
using f32x4  = __attribute__((ext_vector_type(4))) float;

__device__ __forceinline__ uint16_t f2bf(float f) {
  uint32_t u = __builtin_bit_cast(uint32_t, f);
  u += 0x7fffu + ((u >> 16) & 1u);   // round-to-nearest-even
  return (uint16_t)(u >> 16);
}
__device__ __forceinline__ float bf2f(uint16_t h) {
  uint32_t u = ((uint32_t)h) << 16;
  return __builtin_bit_cast(float, u);
}

// agent-scope write-through accesses (coherent at L3)
__device__ __forceinline__ void st32_agent(uint32_t* p, uint32_t v) {
  __hip_atomic_store(p, v, __ATOMIC_RELAXED, __HIP_MEMORY_SCOPE_AGENT);
}
__device__ __forceinline__ void st16_agent(uint16_t* p, uint16_t v) {
  __hip_atomic_store(p, v, __ATOMIC_RELAXED, __HIP_MEMORY_SCOPE_AGENT);
}
__device__ __forceinline__ uint32_t ld32_agent(const uint32_t* p) {
  return __hip_atomic_load(p, __ATOMIC_RELAXED, __HIP_MEMORY_SCOPE_AGENT);
}

// 16B L1/L2-bypassing load (system-coherent): served from L3, never stale.
// Issued WITHOUT a wait; caller must s_waitcnt vmcnt(0) + sched_barrier(0)
// before consuming (rule #18: compiler may hoist MFMAs past asm waits).
#define LDXB(dst, base, IMM)                                              \
  asm volatile("global_load_dwordx4 %0, %1, off offset:" IMM " sc0 sc1"   \
               : "=v"(dst) : "v"(base) : "memory")

// ---- prep kernels ----
__global__ void k_split_w(const float* __restrict__ w, uint16_t* __restrict__ hi,
                          uint16_t* __restrict__ lo, int n) {
  for (int i = blockIdx.x * blockDim.x + threadIdx.x; i < n;
       i += gridDim.x * blockDim.x) {
    float f = w[i];
    uint16_t h = f2bf(f);
    hi[i] = h;
    lo[i] = f2bf(f - bf2f(h));
  }
}

__global__ void k_tobf(const float* __restrict__ src, uint16_t* __restrict__ dst,
                       int n) {
  for (int i = blockIdx.x * blockDim.x + threadIdx.x; i < n;
       i += gridDim.x * blockDim.x)
    dst[i] = f2bf(src[i]);
}

__global__ void k_init_x(const float* __restrict__ init,
                         uint16_t* __restrict__ xb,
                         uint32_t* __restrict__ flags) {
  int i = blockIdx.x * blockDim.x + threadIdx.x;
  if (i < NBLK * 16) flags[i] = 0u;          // 64B-spaced barrier flags
  if (i < B_DIM * R_DIM) xb[i] = f2bf(init[i & (R_DIM - 1)]);
}

// ---- persistent ESN kernel: fence-free bypass reads + per-wave dataflow sync ----
// 256 blocks: bid>>7 = batch half (32 rows), bid&127 = n-tile (16 cols).
// 8 waves: w>>2 = m-subtile (16 rows), w&3 = K-split group kg (512 k each).
// NO global/half barrier. Wave kg consumes x cols [kg*512, kg*512+512) of its
// half, produced by exactly 32 blocks (n-tiles kg*32..kg*32+31); it polls only
// those 32 flags then proceeds. No acquire fence anywhere: x reads are sc0 sc1
// bypass dwordx4 (L3-coherent), x writes are write-through sc1 stores drained
// by vmcnt(0) before the block's flag. WAR on the 2-deep ping-pong: a block's
// 4 K-groups' producer sets union to the WHOLE half, so passing step-(t+2)
// waits implies all readers of buf[(t+1)&1]@t+1 finished (reads precede
// epilogue+flag within a step). Read-only data (Iw,u,W) stays L2-hot forever.
__global__ __launch_bounds__(NTHR, 1)
void k_persist(const uint16_t* __restrict__ Whi, const uint16_t* __restrict__ Wlo,
               const uint16_t* __restrict__ Iwb, const uint16_t* __restrict__ ubf,
               const float* __restrict__ init, uint16_t* __restrict__ xb,
               const float* __restrict__ bias, const int* __restrict__ lengths,
               float* __restrict__ out, uint32_t* __restrict__ flags)
{
  extern __shared__ char smem[];
  uint16_t* s_whi  = (uint16_t*)(smem + S_WHI_OFF);
  uint16_t* s_wlo  = (uint16_t*)(smem + S_WLO_OFF);
  float*    s_part = (float*)(smem + S_PART_OFF);

  const int bid  = blockIdx.x;
  const int h    = bid >> 7;           // batch half
  const int n0   = (bid & 127) * 16;   // output column base
  const int tid  = threadIdx.x;
  const int w    = tid >> 6;
  const int lane = tid & 63;
  const int kg   = w & 3;              // K-split group
  const int mt   = h * 32 + (w >> 2) * 16;  // batch-row tile base
  const int fr   = lane & 15;
  const int koffe = (lane >> 4) << 3;  // 0,8,16,24 element offset

  // preload W slice (16 cols x 2048 k, hi+lo) into LDS, fragment layout
  for (int s = tid; s < 4096; s += NTHR) {
    int ch = s >> 6, l = s & 63;
    size_t g = (size_t)(n0 + (l & 15)) * R_DIM + (size_t)ch * 32 + ((l >> 4) << 3);
    *(short8*)(s_whi + (size_t)s * 8) = *(const short8*)(Whi + g);
    *(short8*)(s_wlo + (size_t)s * 8) = *(const short8*)(Wlo + g);
  }

  // Iw fragments: step-invariant -> registers, loaded ONCE
  short8 biv[6];
  {
    const uint16_t* iw_row = Iwb + (size_t)(n0 + fr) * D_DIM + kg * 192 + koffe;
#pragma unroll
    for (int i = 0; i < 6; ++i) biv[i] = *(const short8*)(iw_row + i * 32);
  }
  __syncthreads();

  // this wave's 32 producer flags (lanes 0..31; lanes 32..63 duplicate)
  const uint32_t* my_flag = flags + (size_t)(h * 128 + kg * 32 + (lane & 31)) * 16;

  // epilogue mapping: 512 threads x 1 element (row r, col c of the 32x16 tile)
  const int r_ep = tid >> 4;           // 0..31
  const int c_ep = tid & 15;           // 0..15
  const int b_ep = h * 32 + r_ep;
  const float bias_ep = bias[n0 + c_ep];
  float xo = init[n0 + c_ep];          // running state in f32 registers
  const int len_ep = lengths[b_ep];
  const int mw_ep = (r_ep >> 4) << 2;                      // wave group base
  const int l_ep  = ((((r_ep & 15) >> 2)) << 4) | c_ep;    // lane within wave
  const int j_ep  = r_ep & 3;

  // prefetch u fragments for step 0
  short8 au[6];
  {
    const uint16_t* u_row = ubf + ((size_t)0 * B_DIM + mt + fr) * D_DIM + kg * 192 + koffe;
#pragma unroll
    for (int i = 0; i < 6; ++i) au[i] = *(const short8*)(u_row + i * 32);
  }

  for (int t = 0; t < T_STEPS; ++t) {
    const int cur = t & 1, nxt = cur ^ 1;

    // ---- per-wave producer wait (dataflow; no fence, no rendezvous) ----
    if (t > 0) {
      const uint32_t tgt = (uint32_t)t;   // producers completed step t-1
      for (;;) {
        bool ok = (ld32_agent(my_flag) >= tgt);
        if (__all(ok)) break;
        __builtin_amdgcn_s_sleep(1);
      }
    }

    // ---- issue ALL 16 bypass x-loads (this wave's 512-col slice) ----
    const uint16_t* xrow = xb + (size_t)cur * B_DIM * R_DIM
                              + (size_t)(mt + fr) * R_DIM + kg * 512 + koffe;
    short8 ahv[16];
    LDXB(ahv[0],  xrow, "0");   LDXB(ahv[1],  xrow, "64");
    LDXB(ahv[2],  xrow, "128"); LDXB(ahv[3],  xrow, "192");
    LDXB(ahv[4],  xrow, "256"); LDXB(ahv[5],  xrow, "320");
    LDXB(ahv[6],  xrow, "384"); LDXB(ahv[7],  xrow, "448");
    LDXB(ahv[8],  xrow, "512"); LDXB(ahv[9],  xrow, "576");
    LDXB(ahv[10], xrow, "640"); LDXB(ahv[11], xrow, "704");
    LDXB(ahv[12], xrow, "768"); LDXB(ahv[13], xrow, "832");
    LDXB(ahv[14], xrow, "896"); LDXB(ahv[15], xrow, "960");

    // ---- input projection (register-only MFMAs fill the load latency) ----
    f32x4 acc = {0.f, 0.f, 0.f, 0.f};
#pragma unroll
    for (int i = 0; i < 6; ++i)
      acc = __builtin_amdgcn_mfma_f32_16x16x32_bf16(au[i], biv[i], acc, 0, 0, 0);

    // all bypass loads landed; fence the scheduler (rule #18)
    asm volatile("s_waitcnt vmcnt(0)" ::: "memory");
    __builtin_amdgcn_sched_barrier(0);

    // ---- recurrent MFMA phase (x_bf16 * (Whi + Wlo), K-split) ----
#pragma unroll 16
    for (int i = 0; i < 16; ++i) {
      const int ch = kg * 16 + i;
      short8 bh = *(const short8*)(s_whi + (size_t)(ch * 64 + lane) * 8);
      short8 bl = *(const short8*)(s_wlo + (size_t)(ch * 64 + lane) * 8);
      acc = __builtin_amdgcn_mfma_f32_16x16x32_bf16(ahv[i], bh, acc, 0, 0, 0);
      acc = __builtin_amdgcn_mfma_f32_16x16x32_bf16(ahv[i], bl, acc, 0, 0, 0);
    }

    // ---- K-split reduce through LDS ----
    *(f32x4*)(s_part + ((size_t)w * 64 + lane) * 4) = acc;
    __syncthreads();

    // ---- epilogue: 1 element/thread; f32 state in regs; bf16 wt store ----
    {
      float pre = bias_ep;
#pragma unroll
      for (int g2 = 0; g2 < 4; ++g2)
        pre += s_part[(mw_ep + g2) * 256 + l_ep * 4 + j_ep];
      float xn = 0.5f * xo + 0.5f * tanhf(pre);
      if (t >= len_ep) xn = 0.0f;
      xo = xn;
      out[((size_t)b_ep * T_STEPS + t) * R_DIM + n0 + c_ep] = xn;  // plain store
      st16_agent(xb + (size_t)nxt * B_DIM * R_DIM + (size_t)b_ep * R_DIM + n0 + c_ep,
                 f2bf(xn));
    }

    if (t == T_STEPS - 1) break;

    // ---- block arrival: all waves' stores acked at L3, then publish flag ----
    asm volatile("s_waitcnt vmcnt(0)" ::: "memory");
    __syncthreads();                   // all 8 waves drained (also s_part WAR)
    if (tid == 0) st32_agent(flags + (size_t)bid * 16, (uint32_t)(t + 1));

    // prefetch next step's u (read-only, L2-hot; overlaps the next poll)
    {
      const uint16_t* u_row = ubf + ((size_t)(t + 1) * B_DIM + mt + fr) * D_DIM + kg * 192 + koffe;
#pragma unroll
      for (int i = 0; i < 6; ++i) au[i] = *(const short8*)(u_row + i * 32);
    }
  }
}

extern "C" void kernel_launch(void* const* d_in, const int* in_sizes, int n_in,
                              void* d_out, int out_size, void* d_ws, size_t ws_size,
                              hipStream_t stream) {
  const float* embedded    = (const float*)d_in[0];
  const int*   lengths     = (const int*)d_in[1];
  const float* input_w     = (const float*)d_in[2];
  const float* reservoir_w = (const float*)d_in[3];
  const float* bias        = (const float*)d_in[4];
  const float* init        = (const float*)d_in[5];
  float* out = (float*)d_out;

  // workspace carve (~44 MB)
  char* p = (char*)d_ws;
  uint16_t* Whi = (uint16_t*)p; p += (size_t)R_DIM * R_DIM * 2;
  uint16_t* Wlo = (uint16_t*)p; p += (size_t)R_DIM * R_DIM * 2;
  uint16_t* Iwb = (uint16_t*)p; p += (size_t)R_DIM * D_DIM * 2;
  uint16_t* ubf = (uint16_t*)p; p += (size_t)T_STEPS * B_DIM * D_DIM * 2;
  uint16_t* xb  = (uint16_t*)p; p += (size_t)2 * B_DIM * R_DIM * 2;
  uint32_t* flags = (uint32_t*)p; p += (size_t)NBLK * 16 * 4;

  k_split_w<<<1024, 256, 0, stream>>>(reservoir_w, Whi, Wlo, R_DIM * R_DIM);
  k_tobf<<<512, 256, 0, stream>>>(input_w, Iwb, R_DIM * D_DIM);
  k_tobf<<<2048, 256, 0, stream>>>(embedded, ubf, T_STEPS * B_DIM * D_DIM);
  k_init_x<<<(B_DIM * R_DIM) / 256, 256, 0, stream>>>(init, xb, flags);

  (void)hipFuncSetAttribute((const void*)k_persist,
                            hipFuncAttributeMaxDynamicSharedMemorySize, S_TOTAL);

  void* args[] = {(void*)&Whi, (void*)&Wlo, (void*)&Iwb, (void*)&ubf,
                  (void*)&init, (void*)&xb, (void*)&bias,
                  (void*)&lengths, (void*)&out, (void*)&flags};
  (void)hipLaunchCooperativeKernel((const void*)k_persist, dim3(NBLK), dim3(NTHR),
                                   args, S_TOTAL, stream);
}